// Round 1
// baseline (2059.883 us; speedup 1.0000x reference)
//
#include <hip/hip_runtime.h>
#include <hip/hip_bf16.h>

// Dims
#define BLr   512      // B*L rows
#define Dm    256
#define DIc   512
#define DOUTc 76416

typedef short bf16x8 __attribute__((ext_vector_type(8)));
typedef float f32x16 __attribute__((ext_vector_type(16)));

__device__ __forceinline__ unsigned short f2bf(float f){
  unsigned u = __builtin_bit_cast(unsigned, f);
  u += 0x7FFFu + ((u >> 16) & 1u);   // RNE
  return (unsigned short)(u >> 16);
}

// ---------------- residual + layernorm (one row of D=256 per block) ----------------
__global__ void ln_res_kernel(const float* __restrict__ hin, float* __restrict__ resid,
                              float* __restrict__ out, const float* __restrict__ w,
                              const float* __restrict__ b, int first)
{
  const int row = blockIdx.x, tid = threadIdx.x;  // 256 threads
  float h = hin[row*Dm + tid];
  float r = first ? h : (resid[row*Dm + tid] + h);
  resid[row*Dm + tid] = r;
  float s = r, s2 = r*r;
  #pragma unroll
  for (int m = 1; m < 64; m <<= 1){
    s  += __shfl_xor(s, m);
    s2 += __shfl_xor(s2, m);
  }
  __shared__ float ls[4], ls2[4];
  if ((tid & 63) == 0){ ls[tid >> 6] = s; ls2[tid >> 6] = s2; }
  __syncthreads();
  float ts = ls[0] + ls[1] + ls[2] + ls[3];
  float t2 = ls2[0] + ls2[1] + ls2[2] + ls2[3];
  float mu  = ts * (1.f/256.f);
  float var = t2 * (1.f/256.f) - mu*mu;
  out[row*Dm + tid] = (r - mu) * rsqrtf(var + 1e-5f) * w[tid] + b[tid];
}

// ---------------- generic fp32 GEMM: C[M,N] = A[M,K] * W[N,K]^T, 32x32 tiles ----------------
__global__ __launch_bounds__(256) void gemm32_kernel(
    float* __restrict__ C, const float* __restrict__ A, const float* __restrict__ W,
    int N, int K)
{
  __shared__ __align__(16) float As[32*20];
  __shared__ __align__(16) float Ws[32*20];
  const int tid = threadIdx.x;
  const int tx = tid & 15, ty = tid >> 4;
  const int n0 = blockIdx.x * 32, m0 = blockIdx.y * 32;
  float a00=0.f, a01=0.f, a10=0.f, a11=0.f;
  for (int k0 = 0; k0 < K; k0 += 16){
    As[ty*20 + tx]      = A[(m0+ty)*K + k0 + tx];
    As[(ty+16)*20 + tx] = A[(m0+ty+16)*K + k0 + tx];
    int w0r = n0 + ty, w1r = n0 + ty + 16;
    Ws[ty*20 + tx]      = (w0r < N) ? W[w0r*K + k0 + tx] : 0.f;
    Ws[(ty+16)*20 + tx] = (w1r < N) ? W[w1r*K + k0 + tx] : 0.f;
    __syncthreads();
    const float4* A4 = (const float4*)As;
    const float4* W4 = (const float4*)Ws;
    #pragma unroll
    for (int kq = 0; kq < 4; ++kq){
      float4 av0 = A4[ty*5 + kq], av1 = A4[(ty+16)*5 + kq];
      float4 wv0 = W4[tx*5 + kq], wv1 = W4[(tx+16)*5 + kq];
      a00 += av0.x*wv0.x + av0.y*wv0.y + av0.z*wv0.z + av0.w*wv0.w;
      a01 += av0.x*wv1.x + av0.y*wv1.y + av0.z*wv1.z + av0.w*wv1.w;
      a10 += av1.x*wv0.x + av1.y*wv0.y + av1.z*wv0.z + av1.w*wv0.w;
      a11 += av1.x*wv1.x + av1.y*wv1.y + av1.z*wv1.z + av1.w*wv1.w;
    }
    __syncthreads();
  }
  int c0 = n0 + tx, c1 = n0 + tx + 16;
  int r0 = m0 + ty, r1 = m0 + ty + 16;
  if (c0 < N){ C[r0*N + c0] = a00; C[r1*N + c0] = a10; }
  if (c1 < N){ C[r0*N + c1] = a01; C[r1*N + c1] = a11; }
}

// ---------------- depthwise causal conv (K=4) + SiLU ----------------
__global__ void conv_silu_kernel(float* __restrict__ xcv, const float* __restrict__ xz,
                                 const float* __restrict__ cw, const float* __restrict__ cb)
{
  const int idx = blockIdx.x*256 + threadIdx.x;   // over BLr*DIc
  const int row = idx >> 9, d = idx & 511;
  const int t = row & 255;
  const float4 w = *(const float4*)(cw + d*4);
  float acc = cb[d];
  const float* xp = xz + (size_t)row*1024 + d;    // x = first half of xz
  if (t >= 3){
    acc += w.x*xp[-3072] + w.y*xp[-2048] + w.z*xp[-1024] + w.w*xp[0];
  } else {
    acc += w.w*xp[0];
    if (t >= 1) acc += w.z*xp[-1024];
    if (t >= 2) acc += w.y*xp[-2048];
  }
  xcv[idx] = acc / (1.f + __expf(-acc));          // silu
}

// ---------------- xproj: dbl[row,48] = xc[row,:512] @ xproj_w^T ----------------
__global__ void xproj_kernel(float* __restrict__ dbl, const float* __restrict__ xcv,
                             const float* __restrict__ xw)
{
  __shared__ __align__(16) float As[512];
  const int row = blockIdx.x, tid = threadIdx.x;  // 64 threads
  #pragma unroll
  for (int i = 0; i < 8; ++i) As[tid + 64*i] = xcv[row*DIc + tid + 64*i];
  __syncthreads();
  if (tid < 48){
    const float4* wr = (const float4*)(xw + tid*DIc);
    const float4* ar = (const float4*)As;
    float acc = 0.f;
    #pragma unroll 8
    for (int k = 0; k < 128; ++k){
      float4 a = ar[k], w = wr[k];
      acc += a.x*w.x + a.y*w.y + a.z*w.z + a.w*w.w;
    }
    dbl[row*48 + tid] = acc;
  }
}

// ---------------- dt = softplus(dbl[:, :16] @ dt_w^T + dt_b) ----------------
__global__ void dtproj_kernel(float* __restrict__ dt, const float* __restrict__ dbl,
                              const float* __restrict__ dw, const float* __restrict__ db)
{
  const int idx = blockIdx.x*256 + threadIdx.x;
  const int m = idx >> 9, n = idx & 511;
  const float4* wr = (const float4*)(dw + n*16);
  float4 w0 = wr[0], w1 = wr[1], w2 = wr[2], w3 = wr[3];
  const float* dr = dbl + m*48;
  float acc = db[n];
  acc += dr[0]*w0.x  + dr[1]*w0.y  + dr[2]*w0.z  + dr[3]*w0.w;
  acc += dr[4]*w1.x  + dr[5]*w1.y  + dr[6]*w1.z  + dr[7]*w1.w;
  acc += dr[8]*w2.x  + dr[9]*w2.y  + dr[10]*w2.z + dr[11]*w2.w;
  acc += dr[12]*w3.x + dr[13]*w3.y + dr[14]*w3.z + dr[15]*w3.w;
  dt[idx] = (acc > 20.f) ? acc : log1pf(__expf(acc));
}

// ---------------- selective scan: wave = 2 channels x 32 states ----------------
__global__ void scan_kernel(float* __restrict__ y, const float* __restrict__ dt,
                            const float* __restrict__ xc, const float* __restrict__ dbl,
                            const float* __restrict__ A_log, const float* __restrict__ Cmat,
                            const float* __restrict__ Dvec)
{
  const int lane = threadIdx.x;               // 64
  const int b = blockIdx.y;
  const int d = blockIdx.x*2 + (lane >> 5);
  const int n = lane & 31;
  const float A  = -__expf(A_log[d*32 + n]);
  const float Cv = Cmat[d*32 + n];
  const float Dv = Dvec[d];
  float h = 0.f;
  const int rbase = b*256;
  #pragma unroll 4
  for (int t = 0; t < 256; ++t){
    const int row = rbase + t;
    float dtv = dt[row*DIc + d];
    float xv  = xc[row*DIc + d];
    float Bv  = dbl[row*48 + 16 + n];
    h = __expf(dtv*A)*h + dtv*Bv*xv;
    float p = h*Cv;
    p += __shfl_xor(p, 1);
    p += __shfl_xor(p, 2);
    p += __shfl_xor(p, 4);
    p += __shfl_xor(p, 8);
    p += __shfl_xor(p, 16);
    if (n == 0) y[row*DIc + d] = p + Dv*xv;
  }
}

// ---------------- truncated-spectrum mix: y += irfft(rfft(x)[:16] * W) ----------------
__global__ void fftmix_kernel(float* __restrict__ y, const float* __restrict__ xc,
                              const float* __restrict__ sr, const float* __restrict__ si)
{
  __shared__ float xs[256], ct[256], st[256], Yr[16], Yi[16], Xr[16], Xi[16];
  const int lane = threadIdx.x;   // 64
  const int d = blockIdx.x;
  const int b = blockIdx.y;
  #pragma unroll
  for (int j = 0; j < 4; ++j){
    int t = lane + 64*j;
    xs[t] = xc[(b*256 + t)*DIc + d];
    float sv, cv;
    __sincosf((float)t * 0.02454369260617026f, &sv, &cv);  // 2*pi/256
    ct[t] = cv; st[t] = sv;
  }
  __syncthreads();
  if (lane < 32){
    const int m = lane & 15, im = lane >> 4;
    float acc = 0.f;
    for (int t = 0; t < 256; ++t){
      int idx = (m*t) & 255;
      acc += xs[t] * (im ? st[idx] : ct[idx]);
    }
    if (im == 0) Xr[m] = acc; else Xi[m] = -acc;   // X = sum x e^{-i w t}
  }
  __syncthreads();
  if (lane < 16){
    const int m = lane;
    float wr = sr[d*16 + m], wi = si[d*16 + m];
    Yr[m] = Xr[m]*wr - Xi[m]*wi;
    Yi[m] = Xr[m]*wi + Xi[m]*wr;
  }
  __syncthreads();
  #pragma unroll
  for (int j = 0; j < 4; ++j){
    int t = lane + 64*j;
    float s0 = 0.5f * Yr[0];                       // irfft ignores Im(Y0)
    #pragma unroll
    for (int m = 1; m < 16; ++m){
      int idx = (m*t) & 255;
      s0 += Yr[m]*ct[idx] - Yi[m]*st[idx];
    }
    y[(b*256 + t)*DIc + d] += s0 * 0.0078125f;     // 2/256
  }
}

// ---------------- gate: g = y * silu(z); also emit bf16 copy ----------------
__global__ void gate_kernel(float* __restrict__ g, unsigned short* __restrict__ gbf,
                            const float* __restrict__ y, const float* __restrict__ xz)
{
  const int idx = blockIdx.x*256 + threadIdx.x;
  const int row = idx >> 9, d = idx & 511;
  float z = xz[row*1024 + 512 + d];
  float gv = y[idx] * (z / (1.f + __expf(-z)));
  g[idx] = gv;
  gbf[idx] = f2bf(gv);
}

// ---------------- final big GEMM: Out[512,76416] = Gb[512,512]bf16 @ W[76416,512]^T ----------------
// MFMA 32x32x16 bf16. 8 waves/block: wave = mq*2+nq, mq in 0..3 (128 rows), nq in 0..1 (32 cols).
// A staged in LDS (pad stride 40 bf16); W converted fp32->bf16 in-register.
__global__ __launch_bounds__(512, 1) void gemm_final_kernel(
    float* __restrict__ Out, const unsigned short* __restrict__ Gb, const float* __restrict__ W)
{
  __shared__ __align__(16) unsigned short As[512*40];   // 40 KB, chunk of 32 k
  const int tid  = threadIdx.x;
  const int wave = tid >> 6, lane = tid & 63;
  const int half = lane >> 5, lm = lane & 31;
  const int nq = wave & 1, mq = wave >> 1;
  const int n0  = blockIdx.x * 64 + nq * 32;
  const int col = n0 + lm;
  const float* Wp = W + (size_t)col * 512;

  f32x16 acc[4];
  #pragma unroll
  for (int i = 0; i < 4; ++i)
    #pragma unroll
    for (int r = 0; r < 16; ++r) acc[i][r] = 0.f;

  const int srow  = tid >> 2;    // 0..127
  const int squad = tid & 3;

  for (int k0 = 0; k0 < 512; k0 += 32){
    // stage A chunk: 512 rows x 32 k (bf16), padded rows of 40
    #pragma unroll
    for (int p = 0; p < 4; ++p){
      int row = srow + p * 128;
      *(uint4*)(&As[row*40 + squad*8]) = *(const uint4*)(Gb + row*512 + k0 + squad*8);
    }
    __syncthreads();
    // B fragments: W[col][k0 + kc*16 + half*8 + j], fp32 -> bf16
    bf16x8 bfr[2];
    #pragma unroll
    for (int kc = 0; kc < 2; ++kc){
      const float* wp = Wp + k0 + kc*16 + half*8;
      float4 wa = *(const float4*)wp;
      float4 wb = *(const float4*)(wp + 4);
      bf16x8 bv;
      bv[0]=(short)f2bf(wa.x); bv[1]=(short)f2bf(wa.y); bv[2]=(short)f2bf(wa.z); bv[3]=(short)f2bf(wa.w);
      bv[4]=(short)f2bf(wb.x); bv[5]=(short)f2bf(wb.y); bv[6]=(short)f2bf(wb.z); bv[7]=(short)f2bf(wb.w);
      bfr[kc] = bv;
    }
    #pragma unroll
    for (int mt = 0; mt < 4; ++mt){
      int row = (mq*4 + mt)*32 + lm;
      #pragma unroll
      for (int kc = 0; kc < 2; ++kc){
        bf16x8 av = *(const bf16x8*)(&As[row*40 + kc*16 + half*8]);
        acc[mt] = __builtin_amdgcn_mfma_f32_32x32x16_bf16(av, bfr[kc], acc[mt], 0, 0, 0);
      }
    }
    __syncthreads();
  }
  #pragma unroll
  for (int mt = 0; mt < 4; ++mt){
    int rbase = (mq*4 + mt)*32 + 4*half;
    #pragma unroll
    for (int r = 0; r < 16; ++r){
      int row = rbase + (r & 3) + 8*(r >> 2);
      Out[(size_t)row * DOUTc + col] = acc[mt][r];
    }
  }
}

// ---------------- host ----------------
extern "C" void kernel_launch(void* const* d_in, const int* in_sizes, int n_in,
                              void* d_out, int out_size, void* d_ws, size_t ws_size,
                              hipStream_t stream)
{
  (void)in_sizes; (void)n_in; (void)out_size; (void)ws_size;
  const float* x       = (const float*)d_in[0];
  const float* ln_w    = (const float*)d_in[1];
  const float* ln_b    = (const float*)d_in[2];
  const float* in_w    = (const float*)d_in[3];
  const float* conv_w  = (const float*)d_in[4];
  const float* conv_b  = (const float*)d_in[5];
  const float* xproj_w = (const float*)d_in[6];
  const float* dt_w    = (const float*)d_in[7];
  const float* dt_b    = (const float*)d_in[8];
  const float* A_log   = (const float*)d_in[9];
  const float* Cmat    = (const float*)d_in[10];
  const float* Dvec    = (const float*)d_in[11];
  const float* spec_r  = (const float*)d_in[12];
  const float* spec_i  = (const float*)d_in[13];
  const float* out_w   = (const float*)d_in[14];
  const float* fln_w   = (const float*)d_in[15];
  const float* fln_b   = (const float*)d_in[16];
  const float* f_in_w  = (const float*)d_in[17];
  const float* f_conv_w= (const float*)d_in[18];
  const float* f_conv_b= (const float*)d_in[19];
  const float* f_xproj = (const float*)d_in[20];
  const float* f_dt_w  = (const float*)d_in[21];
  const float* f_dt_b  = (const float*)d_in[22];
  const float* f_A_log = (const float*)d_in[23];
  const float* f_Cmat  = (const float*)d_in[24];
  const float* f_Dvec  = (const float*)d_in[25];
  const float* f_spec_r= (const float*)d_in[26];
  const float* f_spec_i= (const float*)d_in[27];
  const float* f_out_w = (const float*)d_in[28];

  float* ws   = (float*)d_ws;
  float* resid = ws;                      // 131072
  float* h_ln  = ws + 131072;             // 131072
  float* xz    = ws + 262144;             // 524288
  float* xc    = ws + 786432;             // 262144
  float* dbl   = ws + 1048576;            // 24576
  float* dtb   = ws + 1073152;            // 262144
  float* yb    = ws + 1335296;            // 262144
  float* gb    = ws + 1597440;            // 262144
  float* hid   = ws + 1859584;            // 131072
  unsigned short* g_bf = (unsigned short*)(ws + 1990656);  // 262144 ushort
  float* outp = (float*)d_out;

  for (int i = 0; i < 8; ++i){
    const bool fin = (i == 7);
    const float* lw = fin ? fln_w   : ln_w    + i*256;
    const float* lb = fin ? fln_b   : ln_b    + i*256;
    const float* iw = fin ? f_in_w  : in_w    + i*262144;
    const float* cw = fin ? f_conv_w: conv_w  + i*2048;
    const float* cb = fin ? f_conv_b: conv_b  + i*512;
    const float* xw = fin ? f_xproj : xproj_w + i*24576;
    const float* dw = fin ? f_dt_w  : dt_w    + i*8192;
    const float* db = fin ? f_dt_b  : dt_b    + i*512;
    const float* al = fin ? f_A_log : A_log   + i*16384;
    const float* cm = fin ? f_Cmat  : Cmat    + i*16384;
    const float* dv = fin ? f_Dvec  : Dvec    + i*512;
    const float* sr = fin ? f_spec_r: spec_r  + i*8192;
    const float* si = fin ? f_spec_i: spec_i  + i*8192;

    ln_res_kernel<<<BLr, 256, 0, stream>>>(i==0 ? x : hid, resid, h_ln, lw, lb, i==0 ? 1 : 0);
    gemm32_kernel<<<dim3(32, 16), 256, 0, stream>>>(xz, h_ln, iw, 1024, 256);
    conv_silu_kernel<<<1024, 256, 0, stream>>>(xc, xz, cw, cb);
    xproj_kernel<<<BLr, 64, 0, stream>>>(dbl, xc, xw);
    dtproj_kernel<<<1024, 256, 0, stream>>>(dtb, dbl, dw, db);
    scan_kernel<<<dim3(256, 2), 64, 0, stream>>>(yb, dtb, xc, dbl, al, cm, dv);
    fftmix_kernel<<<dim3(512, 2), 64, 0, stream>>>(yb, xc, sr, si);
    gate_kernel<<<1024, 256, 0, stream>>>(gb, g_bf, yb, xz);
    if (!fin){
      gemm32_kernel<<<dim3(8, 16), 256, 0, stream>>>(hid, gb, out_w + i*131072, 256, 512);
    } else {
      gemm_final_kernel<<<DOUTc/64, 512, 0, stream>>>(outp, g_bf, f_out_w);
    }
  }
}

// Round 3
// 1339.185 us; speedup vs baseline: 1.5382x; 1.5382x over previous
//
#include <hip/hip_runtime.h>
#include <hip/hip_bf16.h>

#define BLr 512
#define Dm 256
#define DIc 512
#define DOUTc 76416

typedef short bf16x8 __attribute__((ext_vector_type(8)));
typedef float f32x16 __attribute__((ext_vector_type(16)));

__device__ __forceinline__ unsigned short f2bf(float f){
  unsigned u = __builtin_bit_cast(unsigned, f);
  u += 0x7FFFu + ((u >> 16) & 1u);   // RNE
  return (unsigned short)(u >> 16);
}

__device__ __forceinline__ void gl_lds16(const void* g, void* l){
  __builtin_amdgcn_global_load_lds(
      (const __attribute__((address_space(1))) unsigned int*)g,
      (__attribute__((address_space(3))) unsigned int*)l, 16, 0, 0);
}

__device__ __forceinline__ bf16x8 cvt8(float4 a, float4 b){
  unsigned q0 = (unsigned)f2bf(a.x) | ((unsigned)f2bf(a.y) << 16);
  unsigned q1 = (unsigned)f2bf(a.z) | ((unsigned)f2bf(a.w) << 16);
  unsigned q2 = (unsigned)f2bf(b.x) | ((unsigned)f2bf(b.y) << 16);
  unsigned q3 = (unsigned)f2bf(b.z) | ((unsigned)f2bf(b.w) << 16);
  uint4 u{q0, q1, q2, q3};
  return __builtin_bit_cast(bf16x8, u);
}

// ---------------- init: resid = x ----------------
__global__ void init_resid_kernel(float* __restrict__ resid, const float* __restrict__ x){
  int i = blockIdx.x*256 + threadIdx.x;
  resid[i] = x[i];
}

// ---------------- K1: fused LN + in-proj. block = 32 rows x 64 cols ----------------
__global__ __launch_bounds__(256) void ln_inproj_kernel(
    float* __restrict__ xz, const float* __restrict__ resid,
    const float* __restrict__ lw, const float* __restrict__ lb,
    const float* __restrict__ iw)
{
  __shared__ __align__(16) float Aln[32][260];  // full K=256, LN'd
  __shared__ __align__(16) float Ws[64][36];    // 64 cols x 32 k chunk
  const int tid = threadIdx.x;
  const int m0 = blockIdx.y*32, n0 = blockIdx.x*64;
  const int wv = tid>>6, lane = tid&63;
  float4 w4 = *(const float4*)(lw + lane*4);
  float4 b4 = *(const float4*)(lb + lane*4);
  #pragma unroll
  for (int rr = 0; rr < 8; ++rr){
    int row = wv*8 + rr;
    float4 v = *(const float4*)(resid + (m0+row)*Dm + lane*4);
    float s  = v.x+v.y+v.z+v.w;
    float s2 = v.x*v.x+v.y*v.y+v.z*v.z+v.w*v.w;
    #pragma unroll
    for (int m = 1; m < 64; m <<= 1){ s += __shfl_xor(s,m); s2 += __shfl_xor(s2,m); }
    float mu = s*(1.f/256.f), var = s2*(1.f/256.f) - mu*mu;
    float rs = rsqrtf(var + 1e-5f);
    float4 o;
    o.x = (v.x-mu)*rs*w4.x + b4.x;
    o.y = (v.y-mu)*rs*w4.y + b4.y;
    o.z = (v.z-mu)*rs*w4.z + b4.z;
    o.w = (v.w-mu)*rs*w4.w + b4.w;
    *(float4*)&Aln[row][lane*4] = o;
  }
  const int ty = tid>>4, tx = tid&15;
  const int col = tid>>2, seg = tid&3;
  float acc[2][4] = {{0,0,0,0},{0,0,0,0}};
  for (int kc = 0; kc < 256; kc += 32){
    const float* wp = iw + (n0+col)*Dm + kc + seg*8;
    __syncthreads();   // also covers Aln writes on first pass
    *(float4*)&Ws[col][seg*8]   = *(const float4*)wp;
    *(float4*)&Ws[col][seg*8+4] = *(const float4*)(wp+4);
    __syncthreads();
    #pragma unroll
    for (int kk = 0; kk < 8; ++kk){
      float4 a0 = *(const float4*)&Aln[ty][kc+kk*4];
      float4 a1 = *(const float4*)&Aln[ty+16][kc+kk*4];
      #pragma unroll
      for (int j = 0; j < 4; ++j){
        float4 w = *(const float4*)&Ws[tx+16*j][kk*4];
        acc[0][j] += a0.x*w.x + a0.y*w.y + a0.z*w.z + a0.w*w.w;
        acc[1][j] += a1.x*w.x + a1.y*w.y + a1.z*w.z + a1.w*w.w;
      }
    }
  }
  #pragma unroll
  for (int j = 0; j < 4; ++j){
    xz[(m0+ty)*1024    + n0 + tx + 16*j] = acc[0][j];
    xz[(m0+ty+16)*1024 + n0 + tx + 16*j] = acc[1][j];
  }
}

// ---------------- K2: conv+SiLU + xproj + dt-proj. block = 1 row ----------------
__global__ __launch_bounds__(256) void conv_xproj_dt_kernel(
    float* __restrict__ xc, float* __restrict__ dbl, float* __restrict__ dtv,
    const float* __restrict__ xz, const float* __restrict__ cw,
    const float* __restrict__ cb, const float* __restrict__ xw,
    const float* __restrict__ dw, const float* __restrict__ db)
{
  __shared__ __align__(16) float xcr[512];
  __shared__ float dblq[16];
  const int row = blockIdx.x, tid = threadIdx.x;
  const int t = row & 255;
  #pragma unroll
  for (int h = 0; h < 2; ++h){
    int d = tid + h*256;
    float4 w = *(const float4*)(cw + d*4);
    float acc = cb[d];
    const float* xp = xz + (size_t)row*1024 + d;
    if (t >= 3) acc += w.x*xp[-3072] + w.y*xp[-2048] + w.z*xp[-1024] + w.w*xp[0];
    else {
      acc += w.w*xp[0];
      if (t >= 1) acc += w.z*xp[-1024];
      if (t >= 2) acc += w.y*xp[-2048];
    }
    float v = acc / (1.f + __expf(-acc));
    xcr[d] = v;
    xc[row*DIc + d] = v;
  }
  __syncthreads();
  const int wv = tid>>6, lane = tid&63;
  float4 xa = *(const float4*)&xcr[lane*4];
  float4 xb = *(const float4*)&xcr[256 + lane*4];
  for (int o = 0; o < 12; ++o){
    int oo = wv*12 + o;
    const float* wr = xw + oo*DIc;
    float4 wa = *(const float4*)(wr + lane*4);
    float4 wb = *(const float4*)(wr + 256 + lane*4);
    float p = xa.x*wa.x + xa.y*wa.y + xa.z*wa.z + xa.w*wa.w
            + xb.x*wb.x + xb.y*wb.y + xb.z*wb.z + xb.w*wb.w;
    #pragma unroll
    for (int m = 1; m < 64; m <<= 1) p += __shfl_xor(p, m);
    if (lane == 0){
      dbl[row*48 + oo] = p;
      if (oo < 16) dblq[oo] = p;
    }
  }
  __syncthreads();
  #pragma unroll
  for (int h = 0; h < 2; ++h){
    int d = tid + h*256;
    const float4* wr = (const float4*)(dw + d*16);
    float4 w0 = wr[0], w1 = wr[1], w2 = wr[2], w3 = wr[3];
    float acc = db[d];
    acc += dblq[0]*w0.x  + dblq[1]*w0.y  + dblq[2]*w0.z  + dblq[3]*w0.w;
    acc += dblq[4]*w1.x  + dblq[5]*w1.y  + dblq[6]*w1.z  + dblq[7]*w1.w;
    acc += dblq[8]*w2.x  + dblq[9]*w2.y  + dblq[10]*w2.z + dblq[11]*w2.w;
    acc += dblq[12]*w3.x + dblq[13]*w3.y + dblq[14]*w3.z + dblq[15]*w3.w;
    dtv[row*DIc + d] = (acc > 20.f) ? acc : log1pf(__expf(acc));
  }
}

// ---------------- K3: scan + spectral mix + gate. block = 8 channels x 1 batch ----------------
__global__ __launch_bounds__(256) void scan_fft_gate_kernel(
    float* __restrict__ g, unsigned short* __restrict__ gbf,
    const float* __restrict__ xc, const float* __restrict__ dtv,
    const float* __restrict__ dbl, const float* __restrict__ xz,
    const float* __restrict__ A_log, const float* __restrict__ Cmat,
    const float* __restrict__ Dvec, const float* __restrict__ sr,
    const float* __restrict__ si)
{
  __shared__ float xs[8][260], dts[8][260], ys[8][260];
  __shared__ float Bs[256][33];
  __shared__ float ct[256], st[256];
  __shared__ float Ysr[8][17], Ysi[8][17];
  const int tid = threadIdx.x;
  const int b = blockIdx.y, d0 = blockIdx.x*8;
  {
    float sv, cv;
    __sincosf((float)tid * 0.02454369260617026f, &sv, &cv);  // 2*pi/256
    ct[tid] = cv; st[tid] = sv;
  }
  const int dd = tid & 7, tq = tid >> 3;
  #pragma unroll
  for (int i = 0; i < 8; ++i){
    int t = i*32 + tq;
    xs[dd][t]  = xc [(b*256+t)*DIc + d0+dd];
    dts[dd][t] = dtv[(b*256+t)*DIc + d0+dd];
  }
  {
    int n = tid & 31, tb = tid >> 5;
    #pragma unroll 4
    for (int i = 0; i < 32; ++i){
      int t = i*8 + tb;
      Bs[t][n] = dbl[(b*256+t)*48 + 16 + n];
    }
  }
  __syncthreads();
  const int wv = tid>>6, lane = tid&63;
  {  // scan: wave = 2 channels x 32 states, all operands in LDS
    const int ddw = wv*2 + (lane>>5);
    const int d = d0 + ddw;
    const int n = lane & 31;
    const float A  = -__expf(A_log[d*32+n]);
    const float Cv = Cmat[d*32+n];
    float h = 0.f;
    #pragma unroll 4
    for (int t = 0; t < 256; ++t){
      float dtl = dts[ddw][t];
      float xv  = xs[ddw][t];
      float Bv  = Bs[t][n];
      h = __expf(dtl*A)*h + dtl*Bv*xv;
      float p = h*Cv;
      p += __shfl_xor(p,1); p += __shfl_xor(p,2); p += __shfl_xor(p,4);
      p += __shfl_xor(p,8); p += __shfl_xor(p,16);
      if (n == 0) ys[ddw][t] = p;
    }
  }
  {  // 16-bin DFT: wave = 2 channels x (16 bins x re/im)
    const int ddw = wv*2 + (lane>>5);
    const int m = lane & 15, im = (lane>>4) & 1;
    float acc = 0.f;
    for (int t = 0; t < 256; ++t){
      int idx = (m*t) & 255;
      acc += xs[ddw][t] * (im ? st[idx] : ct[idx]);
    }
    float other = __shfl_xor(acc, 16);
    const int d = d0 + ddw;
    float wr = sr[d*16+m], wi = si[d*16+m];
    if (im == 0){
      float Xr = acc, Xi = -other;
      Ysr[ddw][m] = Xr*wr - Xi*wi;
    } else {
      float Xi = -acc, Xr = other;
      Ysi[ddw][m] = Xr*wi + Xi*wr;
    }
  }
  __syncthreads();
  {  // synthesis + Dvec + gate, coalesced-ish write
    const float Dv = Dvec[d0+dd];
    float yr[16], yi[16];
    #pragma unroll
    for (int m = 0; m < 16; ++m){ yr[m] = Ysr[dd][m]; yi[m] = Ysi[dd][m]; }
    #pragma unroll 2
    for (int i = 0; i < 8; ++i){
      int t = i*32 + tq;
      float fv = 0.5f * yr[0];
      #pragma unroll
      for (int m = 1; m < 16; ++m){
        int idx = (m*t) & 255;
        fv += yr[m]*ct[idx] - yi[m]*st[idx];
      }
      float yv = ys[dd][t] + Dv*xs[dd][t] + fv*0.0078125f;
      float z = xz[(b*256+t)*1024 + 512 + d0+dd];
      float gv = yv * (z / (1.f + __expf(-z)));
      int oi = (b*256+t)*DIc + d0+dd;
      g[oi] = gv;
      gbf[oi] = f2bf(gv);
    }
  }
}

// ---------------- K4: out-proj + residual update. tile 32x32, K=512 ----------------
__global__ __launch_bounds__(256) void outproj_resid_kernel(
    float* __restrict__ resid, const float* __restrict__ g, const float* __restrict__ ow)
{
  __shared__ __align__(16) float As[32][36];
  __shared__ __align__(16) float Ws2[32][36];
  const int tid = threadIdx.x;
  const int n0 = blockIdx.x*32, m0 = blockIdx.y*32;
  const int r = tid>>3, c8 = (tid&7)*4;
  const int ty = tid>>4, tx = tid&15;
  float a00=0,a01=0,a10=0,a11=0;
  for (int kc = 0; kc < 512; kc += 32){
    __syncthreads();
    *(float4*)&As[r][c8]  = *(const float4*)(g  + (m0+r)*DIc + kc + c8);
    *(float4*)&Ws2[r][c8] = *(const float4*)(ow + (n0+r)*DIc + kc + c8);
    __syncthreads();
    #pragma unroll
    for (int kk = 0; kk < 8; ++kk){
      float4 a0 = *(const float4*)&As[ty][kk*4];
      float4 a1 = *(const float4*)&As[ty+16][kk*4];
      float4 w0 = *(const float4*)&Ws2[tx][kk*4];
      float4 w1 = *(const float4*)&Ws2[tx+16][kk*4];
      a00 += a0.x*w0.x + a0.y*w0.y + a0.z*w0.z + a0.w*w0.w;
      a01 += a0.x*w1.x + a0.y*w1.y + a0.z*w1.z + a0.w*w1.w;
      a10 += a1.x*w0.x + a1.y*w0.y + a1.z*w0.z + a1.w*w0.w;
      a11 += a1.x*w1.x + a1.y*w1.y + a1.z*w1.z + a1.w*w1.w;
    }
  }
  resid[(m0+ty)*Dm    + n0+tx]    += a00;
  resid[(m0+ty)*Dm    + n0+tx+16] += a01;
  resid[(m0+ty+16)*Dm + n0+tx]    += a10;
  resid[(m0+ty+16)*Dm + n0+tx+16] += a11;
}

// ---------------- K4f: final GEMM Out[512,76416] = G(bf16) @ W^T ----------------
// 8 waves = 4 mq x 2 nq. K-chunk 64, A staged via global_load_lds with XOR swizzle
// (slot of (row r, 16B-chunk c) = r*8 + (c ^ (r&7)) -> conflict-free b128 reads, no pad).
__global__ __launch_bounds__(512) void gemm_final2_kernel(
    float* __restrict__ Out, const unsigned short* __restrict__ Gb,
    const float* __restrict__ W)
{
  __shared__ __align__(16) unsigned short As[32768];  // 64 KB: 512 rows x 64 k
  const int tid = threadIdx.x;
  const int wv = tid>>6, lane = tid&63;
  const int half = lane>>5, lm = lane&31;
  const int nq = wv & 1, mq = wv >> 1;
  const int col = blockIdx.x*64 + nq*32 + lm;
  const float* Wp = W + (size_t)col*512;
  f32x16 acc[4];
  #pragma unroll
  for (int i = 0; i < 4; ++i)
    #pragma unroll
    for (int rg = 0; rg < 16; ++rg) acc[i][rg] = 0.f;

  for (int k0 = 0; k0 < 512; k0 += 64){
    // async stage A chunk (swizzled)
    #pragma unroll
    for (int p = 0; p < 8; ++p){
      int R  = p*64 + wv*8;                      // wave-uniform base row
      int rr = R + (lane>>3);
      int cg = (lane&7) ^ (rr&7);
      gl_lds16(Gb + rr*512 + k0 + cg*8, (void*)((char*)As + R*128));
    }
    // W loads: 256 B contiguous per lane per chunk
    float4 wf[8];
    #pragma unroll
    for (int j = 0; j < 4; ++j){
      wf[j*2]   = *(const float4*)(Wp + k0 + j*16 + half*8);
      wf[j*2+1] = *(const float4*)(Wp + k0 + j*16 + half*8 + 4);
    }
    __syncthreads();
    #pragma unroll
    for (int j = 0; j < 4; ++j){
      bf16x8 bv = cvt8(wf[j*2], wf[j*2+1]);
      const int c = j*2 + half;
      #pragma unroll
      for (int mt = 0; mt < 4; ++mt){
        int rr = mq*128 + mt*32 + lm;
        bf16x8 av = *(const bf16x8*)((const char*)As + (rr*8 + (c ^ (rr&7)))*16);
        acc[mt] = __builtin_amdgcn_mfma_f32_32x32x16_bf16(av, bv, acc[mt], 0, 0, 0);
      }
    }
    __syncthreads();
  }
  #pragma unroll
  for (int mt = 0; mt < 4; ++mt){
    int rbase = mq*128 + mt*32 + 4*half;
    #pragma unroll
    for (int rg = 0; rg < 16; ++rg){
      int row = rbase + (rg&3) + 8*(rg>>2);
      Out[(size_t)row*DOUTc + col] = acc[mt][rg];
    }
  }
}

// ---------------- host ----------------
extern "C" void kernel_launch(void* const* d_in, const int* in_sizes, int n_in,
                              void* d_out, int out_size, void* d_ws, size_t ws_size,
                              hipStream_t stream)
{
  (void)in_sizes; (void)n_in; (void)out_size; (void)ws_size;
  const float* x       = (const float*)d_in[0];
  const float* ln_w    = (const float*)d_in[1];
  const float* ln_b    = (const float*)d_in[2];
  const float* in_w    = (const float*)d_in[3];
  const float* conv_w  = (const float*)d_in[4];
  const float* conv_b  = (const float*)d_in[5];
  const float* xproj_w = (const float*)d_in[6];
  const float* dt_w    = (const float*)d_in[7];
  const float* dt_b    = (const float*)d_in[8];
  const float* A_log   = (const float*)d_in[9];
  const float* Cmat    = (const float*)d_in[10];
  const float* Dvec    = (const float*)d_in[11];
  const float* spec_r  = (const float*)d_in[12];
  const float* spec_i  = (const float*)d_in[13];
  const float* out_w   = (const float*)d_in[14];
  const float* fln_w   = (const float*)d_in[15];
  const float* fln_b   = (const float*)d_in[16];
  const float* f_in_w  = (const float*)d_in[17];
  const float* f_conv_w= (const float*)d_in[18];
  const float* f_conv_b= (const float*)d_in[19];
  const float* f_xproj = (const float*)d_in[20];
  const float* f_dt_w  = (const float*)d_in[21];
  const float* f_dt_b  = (const float*)d_in[22];
  const float* f_A_log = (const float*)d_in[23];
  const float* f_Cmat  = (const float*)d_in[24];
  const float* f_Dvec  = (const float*)d_in[25];
  const float* f_spec_r= (const float*)d_in[26];
  const float* f_spec_i= (const float*)d_in[27];
  const float* f_out_w = (const float*)d_in[28];

  float* ws   = (float*)d_ws;
  float* resid = ws;                      // 131072
  float* xz    = ws + 131072;             // 524288
  float* xcb   = ws + 655360;             // 262144
  float* dblb  = ws + 917504;             // 24576
  float* dtb   = ws + 942080;             // 262144
  float* gb    = ws + 1204224;            // 262144
  unsigned short* g_bf = (unsigned short*)(ws + 1466368);  // 262144 ushort
  float* outp = (float*)d_out;

  init_resid_kernel<<<512, 256, 0, stream>>>(resid, x);

  for (int i = 0; i < 8; ++i){
    const bool fin = (i == 7);
    const float* lw = fin ? fln_w   : ln_w    + i*256;
    const float* lb = fin ? fln_b   : ln_b    + i*256;
    const float* iw = fin ? f_in_w  : in_w    + i*262144;
    const float* cw = fin ? f_conv_w: conv_w  + i*2048;
    const float* cb = fin ? f_conv_b: conv_b  + i*512;
    const float* xw = fin ? f_xproj : xproj_w + i*24576;
    const float* dw = fin ? f_dt_w  : dt_w    + i*8192;
    const float* db = fin ? f_dt_b  : dt_b    + i*512;
    const float* al = fin ? f_A_log : A_log   + i*16384;
    const float* cm = fin ? f_Cmat  : Cmat    + i*16384;
    const float* dv = fin ? f_Dvec  : Dvec    + i*512;
    const float* sr = fin ? f_spec_r: spec_r  + i*8192;
    const float* si = fin ? f_spec_i: spec_i  + i*8192;

    ln_inproj_kernel<<<dim3(16, 16), 256, 0, stream>>>(xz, resid, lw, lb, iw);
    conv_xproj_dt_kernel<<<512, 256, 0, stream>>>(xcb, dblb, dtb, xz, cw, cb, xw, dw, db);
    scan_fft_gate_kernel<<<dim3(64, 2), 256, 0, stream>>>(gb, g_bf, xcb, dtb, dblb, xz,
                                                          al, cm, dv, sr, si);
    if (!fin){
      outproj_resid_kernel<<<dim3(8, 16), 256, 0, stream>>>(resid, gb, out_w + i*131072);
    } else {
      gemm_final2_kernel<<<DOUTc/64, 512, 0, stream>>>(outp, g_bf, f_out_w);
    }
  }
}